// Round 7
// baseline (295.231 us; speedup 1.0000x reference)
//
#include <hip/hip_runtime.h>
#include <math.h>

#define NB 32
#define CB 256
#define HB 56
#define WB 56
#define PLANE 3136           // floats per (n,c) plane
#define PLANE4 784           // float4 per plane
#define CL 56
#define POOLSZ (NB*CB*CL)
#define NCHUNK 1024          // 8-plane chunks
#define TBLN 1792            // (fallback) table floats per chunk

__device__ inline float wave_sum(float v) {
    #pragma unroll
    for (int o = 32; o; o >>= 1) v += __shfl_xor(v, o, 64);
    return v;
}

// relaxed agent-scope (coherence-point) accessors: sc0/sc1 bypass, NO cache
// maintenance instructions emitted (unlike acquire/release -> buffer_wbl2).
__device__ inline float coh_load(const float* p) {
    return __hip_atomic_load(p, __ATOMIC_RELAXED, __HIP_MEMORY_SCOPE_AGENT);
}
__device__ inline void coh_store(float* p, float v) {
    __hip_atomic_store(p, v, __ATOMIC_RELAXED, __HIP_MEMORY_SCOPE_AGENT);
}

struct KP {
    const float *x, *w1, *b1, *gamma, *beta, *rmean, *rvar;
    const float *wh, *bh, *ww, *bw, *gw1, *gw2, *gb2, *cw1, *cw2, *cb2;
    float *ph, *pw, *mh, *mw, *gap, *tvec, *sbuf, *ybuf, *gbuf;
    int *sync;               // counter0[32] | counter2[32] | flag1[32] | flag2[32]
    float *out;
};

// ================= single cooperative kernel, fence-free per-n relays ===========
__global__ __launch_bounds__(256, 4) void k_one(KP P) {
    __shared__ float smem[6384];              // 25.5 KB: tile / yl|w1t|tb union
    __shared__ float red[256], tvl[256];
    __shared__ float hid[64], part[32], sS[8], gg[2];
    __shared__ int lastf, lastf2;
    const int t = threadIdx.x, wv = t >> 6, ln = t & 63;
    const int gq = blockIdx.x;
    const int n = gq >> 5, c0 = (gq & 31) * 8;
    const int q0 = gq * 8;
    int* counter0 = P.sync;
    int* counter2 = P.sync + 32;
    int* flag1    = P.sync + 64;
    int* flag2    = P.sync + 96;

    // ---- Phase A: pool own 8 planes (4 rounds x 2 planes; verified body) -------
    for (int r = 0; r < 4; ++r) {
        if (r) __syncthreads();               // protect tile reuse
        const int pA = q0 + 2 * r;
        const float4* x4 = (const float4*)(P.x + (size_t)pA * PLANE);
        for (int j = t; j < 2 * PLANE4; j += 256) {
            float4 v = x4[j];
            int pl = j >= PLANE4, jj = j - pl * PLANE4;
            int h = jj / 14, wq = jj - h * 14;
            float* d = &smem[pl * 3192 + h * 57 + wq * 4];
            d[0] = v.x; d[1] = v.y; d[2] = v.z; d[3] = v.w;
        }
        __syncthreads();
        const int pl = wv >> 1;               // waves 0,1 -> plane A; 2,3 -> B
        const float* tbp = &smem[pl * 3192];
        const size_t pidx = (size_t)(pA + pl) * CL;
        if (!(wv & 1)) {                      // even wave: column scans
            if (ln < CL) {
                float s = 0.f, m = -INFINITY;
                #pragma unroll 8
                for (int h = 0; h < HB; ++h) { float vv = tbp[h * 57 + ln]; s += vv; m = fmaxf(m, vv); }
                coh_store(&P.pw[pidx + ln], s * (1.f / HB));
                coh_store(&P.mw[pidx + ln], m);
            }
        } else {                              // odd wave: row scans + gap
            float s = 0.f, m = -INFINITY;
            if (ln < CL) {
                #pragma unroll 8
                for (int wq = 0; wq < WB; ++wq) { float vv = tbp[ln * 57 + wq]; s += vv; m = fmaxf(m, vv); }
                coh_store(&P.ph[pidx + ln], s * (1.f / WB));
                coh_store(&P.mh[pidx + ln], m);
            }
            float tot = wave_sum(s);          // lanes >=56 contribute 0
            if (ln == 0) coh_store(&P.gap[pA + pl], tot * (1.f / PLANE));
        }
    }
    __syncthreads();                          // barrier drain: pool stores acked
    if (t == 0)
        lastf = (__hip_atomic_fetch_add(&counter0[n], 1, __ATOMIC_RELAXED,
                                        __HIP_MEMORY_SCOPE_AGENT) == 31);
    __syncthreads();

    float* yl  = smem;                        // [1792] y[br][m][l]
    float* w1t = smem + 2048;                 // [2048] leader scratch
    float* tb  = smem + 4096;                 // [1792] tables

    if (lastf) {
        // ---- relay-1 leader: gate + y for this n (verified R6 bodies) ----------
        for (int i = t; i < 2048; i += 256) w1t[i] = P.w1[(i & 7) * CB + (i >> 3)];
        {
            int j = t & 63, ch = t >> 6;
            float a = 0.f;
            #pragma unroll 8
            for (int c = 0; c < 64; ++c)
                a += coh_load(&P.gap[n * CB + ch * 64 + c]) * P.gw1[(size_t)j * CB + ch * 64 + c];
            red[j * 4 + ch] = a;
        }
        __syncthreads();                      // w1t + red ready
        if (t < 64)
            hid[t] = fmaxf(red[t * 4] + red[t * 4 + 1] + red[t * 4 + 2] + red[t * 4 + 3], 0.f);
        if (t < 224) {                        // staging-free y einsum
            const int br = t / 112, l = t - br * 112;
            const int lofs = (l < 56) ? l : l - 56;
            const float* pb = (br == 0) ? (l < 56 ? P.ph : P.pw) : (l < 56 ? P.mh : P.mw);
            const float* pp = pb + (size_t)n * (CB * CL) + lofs;
            float acc[8] = {0.f, 0.f, 0.f, 0.f, 0.f, 0.f, 0.f, 0.f};
            #pragma unroll 4
            for (int c = 0; c < CB; ++c) {
                float v = coh_load(&pp[c * CL]);
                float4 wa = *(const float4*)&w1t[c * 8];
                float4 wb = *(const float4*)&w1t[c * 8 + 4];
                acc[0] += v * wa.x; acc[1] += v * wa.y;
                acc[2] += v * wa.z; acc[3] += v * wa.w;
                acc[4] += v * wb.x; acc[5] += v * wb.y;
                acc[6] += v * wb.z; acc[7] += v * wb.w;
            }
            #pragma unroll
            for (int m = 0; m < 8; ++m) {
                float scale = P.gamma[m] * rsqrtf(P.rvar[m] + 1e-5f);
                float val = (acc[m] + P.b1[m] - P.rmean[m]) * scale + P.beta[m];
                yl[br * 896 + m * 112 + l] = fmaxf(val, 0.f);
            }
        }
        __syncthreads();                      // yl + hid ready
        if (wv == 0) {                        // gate softmax via wave-0 shuffle
            float h = hid[ln];
            float p0 = wave_sum(h * P.gw2[ln]);
            float p1 = wave_sum(h * P.gw2[64 + ln]);
            if (ln == 0) {
                float l0 = P.gb2[0] + p0, l1 = P.gb2[1] + p1;
                float mx = fmaxf(l0, l1);
                float e0 = __expf(l0 - mx), e1 = __expf(l1 - mx);
                float inv = 1.f / (e0 + e1);
                gg[0] = e0 * inv; gg[1] = e1 * inv;
            }
        }
        __syncthreads();                      // gg ready
        for (int i = t; i < 1792; i += 256) coh_store(&P.ybuf[n * 1792 + i], yl[i]);
        if (t < 2) coh_store(&P.gbuf[n * 2 + t], gg[t]);
        __syncthreads();                      // drain publish stores
        if (t == 0)
            __hip_atomic_store(&flag1[n], 1, __ATOMIC_RELAXED, __HIP_MEMORY_SCOPE_AGENT);
    } else {
        if (t == 0) {
            while (__hip_atomic_load(&flag1[n], __ATOMIC_RELAXED,
                                     __HIP_MEMORY_SCOPE_AGENT) == 0)
                __builtin_amdgcn_s_sleep(8);
        }
        __syncthreads();
        for (int i = t; i < 1792; i += 256) yl[i] = coh_load(&P.ybuf[n * 1792 + i]);
        if (t < 2) gg[t] = coh_load(&P.gbuf[n * 2 + t]);
        __syncthreads();
    }

    // ---- tables for own 8 channels (verified R6 body) ---------------------------
    {
        const float g0 = gg[0], g1 = gg[1];
        for (int task = t; task < 448; task += 256) {
            int ci = task / 56, l2 = task - ci * 56;
            int c = c0 + ci;
            float h0 = P.bh[c], w0 = P.bw[c], h1 = h0, w1v = w0;
            #pragma unroll
            for (int m = 0; m < 8; ++m) {
                float whv = P.wh[c * 8 + m], wwv = P.ww[c * 8 + m];
                h0  += yl[m * 112 + l2]            * whv;
                w0  += yl[m * 112 + 56 + l2]       * wwv;
                h1  += yl[896 + m * 112 + l2]      * whv;
                w1v += yl[896 + m * 112 + 56 + l2] * wwv;
            }
            tb[task]        = 1.f / (1.f + __expf(-h0));
            tb[448 + task]  = g0 / (1.f + __expf(-w0));
            tb[896 + task]  = 1.f / (1.f + __expf(-h1));
            tb[1344 + task] = g1 / (1.f + __expf(-w1v));
        }
    }
    __syncthreads();

    const float* cH0 = tb;
    const float* cW0 = tb + 448;
    const float* cH1 = tb + 896;
    const float* cW1 = tb + 1344;

    // ---- tsum over own 8 planes (verified body) --------------------------------
    #pragma unroll 1
    for (int i = 0; i < 8; ++i) {
        const float4* xp4 = (const float4*)(P.x + (size_t)(q0 + i) * PLANE);
        const float4* a4 = (const float4*)(cW0 + i * 56);
        const float4* b4 = (const float4*)(cW1 + i * 56);
        const float* h0p = cH0 + i * 56;
        const float* h1p = cH1 + i * 56;
        float acc = 0.f;
        for (int j = t; j < PLANE4; j += 256) {
            float4 v = xp4[j];
            int h = j / 14, wq = j - h * 14;
            float h0 = h0p[h], h1 = h1p[h];
            float4 a = a4[wq], b = b4[wq];
            acc += v.x * (h0 * a.x + h1 * b.x) + v.y * (h0 * a.y + h1 * b.y)
                 + v.z * (h0 * a.z + h1 * b.z) + v.w * (h0 * a.w + h1 * b.w);
        }
        float s = wave_sum(acc);
        if (ln == 0) part[i * 4 + wv] = s;
    }
    __syncthreads();
    if (t < 8)
        coh_store(&P.tvec[q0 + t],
                  (part[t * 4] + part[t * 4 + 1] + part[t * 4 + 2] + part[t * 4 + 3]) * (1.f / PLANE));
    __syncthreads();                          // drain tvec stores
    if (t == 0)
        lastf2 = (__hip_atomic_fetch_add(&counter2[n], 1, __ATOMIC_RELAXED,
                                         __HIP_MEMORY_SCOPE_AGENT) == 31);
    __syncthreads();

    if (lastf2) {
        // ---- relay-2 leader: s[256] for this n (verified pattern) --------------
        tvl[t] = coh_load(&P.tvec[n * CB + t]);
        __syncthreads();
        {
            int j = t & 63, ch = t >> 6;
            float a = 0.f;
            #pragma unroll 8
            for (int c = 0; c < 64; ++c)
                a += tvl[ch * 64 + c] * P.cw1[(size_t)j * CB + ch * 64 + c];
            red[j * 4 + ch] = a;
        }
        __syncthreads();
        if (t < 64)
            hid[t] = fmaxf(red[t * 4] + red[t * 4 + 1] + red[t * 4 + 2] + red[t * 4 + 3], 0.f);
        __syncthreads();
        {
            float a = P.cb2[t];
            #pragma unroll 8
            for (int j = 0; j < 64; ++j) a += hid[j] * P.cw2[t * 64 + j];
            coh_store(&P.sbuf[n * CB + t], 1.f / (1.f + __expf(-a)));
        }
        __syncthreads();                      // drain sbuf stores
        if (t == 0)
            __hip_atomic_store(&flag2[n], 1, __ATOMIC_RELAXED, __HIP_MEMORY_SCOPE_AGENT);
    } else {
        if (t == 0) {
            while (__hip_atomic_load(&flag2[n], __ATOMIC_RELAXED,
                                     __HIP_MEMORY_SCOPE_AGENT) == 0)
                __builtin_amdgcn_s_sleep(8);
        }
        __syncthreads();
    }
    if (t < 8) sS[t] = coh_load(&P.sbuf[n * CB + c0 + t]);
    __syncthreads();

    // ---- final: out = x*(attn*s+1) over own 8 planes (verified body) -----------
    #pragma unroll 1
    for (int i = 0; i < 8; ++i) {
        const float sv = sS[i];
        const float4* xp4 = (const float4*)(P.x + (size_t)(q0 + i) * PLANE);
        float4* op4 = (float4*)(P.out + (size_t)(q0 + i) * PLANE);
        const float4* a4 = (const float4*)(cW0 + i * 56);
        const float4* b4 = (const float4*)(cW1 + i * 56);
        const float* h0p = cH0 + i * 56;
        const float* h1p = cH1 + i * 56;
        for (int j = t; j < PLANE4; j += 256) {
            float4 v = xp4[j];
            int h = j / 14, wq = j - h * 14;
            float h0 = h0p[h] * sv, h1 = h1p[h] * sv;
            float4 a = a4[wq], b = b4[wq];
            float4 rr;
            rr.x = v.x * (h0 * a.x + h1 * b.x + 1.f);
            rr.y = v.y * (h0 * a.y + h1 * b.y + 1.f);
            rr.z = v.z * (h0 * a.z + h1 * b.z + 1.f);
            rr.w = v.w * (h0 * a.w + h1 * b.w + 1.f);
            op4[j] = rr;
        }
    }
}

// =========================== fallback: verified R6 3-kernel path ================

__global__ __launch_bounds__(256) void k_pool(const float* __restrict__ x,
        float* __restrict__ ph, float* __restrict__ pw,
        float* __restrict__ mh, float* __restrict__ mw, float* __restrict__ gap) {
    __shared__ float tile[2 * 3192];
    const int t = threadIdx.x, wv = t >> 6, ln = t & 63;
    const int pA = blockIdx.x * 2;
    const float4* x4 = (const float4*)(x + (size_t)pA * PLANE);
    for (int j = t; j < 2 * PLANE4; j += 256) {
        float4 v = x4[j];
        int pl = j >= PLANE4, jj = j - pl * PLANE4;
        int h = jj / 14, wq = jj - h * 14;
        float* d = &tile[pl * 3192 + h * 57 + wq * 4];
        d[0] = v.x; d[1] = v.y; d[2] = v.z; d[3] = v.w;
    }
    __syncthreads();
    const int pl = wv >> 1;
    const float* tb = &tile[pl * 3192];
    const size_t pidx = (size_t)(pA + pl) * CL;
    if (!(wv & 1)) {
        if (ln < CL) {
            float s = 0.f, m = -INFINITY;
            #pragma unroll 8
            for (int h = 0; h < HB; ++h) { float vv = tb[h * 57 + ln]; s += vv; m = fmaxf(m, vv); }
            pw[pidx + ln] = s * (1.f / HB);
            mw[pidx + ln] = m;
        }
    } else {
        float s = 0.f, m = -INFINITY;
        if (ln < CL) {
            #pragma unroll 8
            for (int wq = 0; wq < WB; ++wq) { float vv = tb[ln * 57 + wq]; s += vv; m = fmaxf(m, vv); }
            ph[pidx + ln] = s * (1.f / WB);
            mh[pidx + ln] = m;
        }
        float tot = wave_sum(s);
        if (ln == 0) gap[pA + pl] = tot * (1.f / PLANE);
    }
}

__global__ __launch_bounds__(256) void k_bt(const float* __restrict__ x,
        const float* __restrict__ ph, const float* __restrict__ pw,
        const float* __restrict__ mh, const float* __restrict__ mw,
        const float* __restrict__ gap,
        const float* __restrict__ w1, const float* __restrict__ b1,
        const float* __restrict__ gamma, const float* __restrict__ beta,
        const float* __restrict__ rmean, const float* __restrict__ rvar,
        const float* __restrict__ gw1, const float* __restrict__ gw2,
        const float* __restrict__ gb2,
        const float* __restrict__ wh, const float* __restrict__ bh,
        const float* __restrict__ ww, const float* __restrict__ bw,
        float* __restrict__ tvec, float* __restrict__ tbl) {
    __shared__ __align__(16) float w1t[CB * 8];
    __shared__ float yl[1792];
    __shared__ __align__(16) float tb[1792];
    __shared__ float red[256];
    __shared__ float hid[64];
    __shared__ float part[32];
    __shared__ float gg[2];
    const int t = threadIdx.x, wv = t >> 6, ln = t & 63;
    const int gq = blockIdx.x;
    const int n = gq >> 5, c0 = (gq & 31) * 8;
    const int q0 = gq * 8;

    for (int i = t; i < CB * 8; i += 256) w1t[i] = w1[(i & 7) * CB + (i >> 3)];
    {
        int j = t & 63, ch = t >> 6;
        const float* gv = gap + n * CB + ch * 64;
        const float* wp = gw1 + (size_t)j * CB + ch * 64;
        float a = 0.f;
        #pragma unroll 8
        for (int c = 0; c < 64; ++c) a += gv[c] * wp[c];
        red[j * 4 + ch] = a;
    }
    __syncthreads();
    if (t < 64)
        hid[t] = fmaxf(red[t * 4] + red[t * 4 + 1] + red[t * 4 + 2] + red[t * 4 + 3], 0.f);
    if (t < 224) {
        const int br = t / 112, l = t - br * 112;
        const int lofs = (l < 56) ? l : l - 56;
        const float* pb = (br == 0) ? (l < 56 ? ph : pw) : (l < 56 ? mh : mw);
        const float* pp = pb + (size_t)n * (CB * CL) + lofs;
        float acc[8] = {0.f, 0.f, 0.f, 0.f, 0.f, 0.f, 0.f, 0.f};
        #pragma unroll 4
        for (int c = 0; c < CB; ++c) {
            float v = pp[c * CL];
            float4 wa = *(const float4*)&w1t[c * 8];
            float4 wb = *(const float4*)&w1t[c * 8 + 4];
            acc[0] += v * wa.x; acc[1] += v * wa.y;
            acc[2] += v * wa.z; acc[3] += v * wa.w;
            acc[4] += v * wb.x; acc[5] += v * wb.y;
            acc[6] += v * wb.z; acc[7] += v * wb.w;
        }
        #pragma unroll
        for (int m = 0; m < 8; ++m) {
            float scale = gamma[m] * rsqrtf(rvar[m] + 1e-5f);
            float val = (acc[m] + b1[m] - rmean[m]) * scale + beta[m];
            yl[br * 896 + m * 112 + l] = fmaxf(val, 0.f);
        }
    }
    __syncthreads();
    if (wv == 0) {
        float h = hid[ln];
        float p0 = wave_sum(h * gw2[ln]);
        float p1 = wave_sum(h * gw2[64 + ln]);
        if (ln == 0) {
            float l0 = gb2[0] + p0, l1 = gb2[1] + p1;
            float mx = fmaxf(l0, l1);
            float e0 = __expf(l0 - mx), e1 = __expf(l1 - mx);
            float inv = 1.f / (e0 + e1);
            gg[0] = e0 * inv; gg[1] = e1 * inv;
        }
    }
    __syncthreads();
    {
        const float g0 = gg[0], g1 = gg[1];
        for (int task = t; task < 448; task += 256) {
            int ci = task / 56, l2 = task - ci * 56;
            int c = c0 + ci;
            float h0 = bh[c], w0 = bw[c], h1 = h0, w1v = w0;
            #pragma unroll
            for (int m = 0; m < 8; ++m) {
                float whv = wh[c * 8 + m], wwv = ww[c * 8 + m];
                h0  += yl[m * 112 + l2]            * whv;
                w0  += yl[m * 112 + 56 + l2]       * wwv;
                h1  += yl[896 + m * 112 + l2]      * whv;
                w1v += yl[896 + m * 112 + 56 + l2] * wwv;
            }
            tb[task]        = 1.f / (1.f + __expf(-h0));
            tb[448 + task]  = g0 / (1.f + __expf(-w0));
            tb[896 + task]  = 1.f / (1.f + __expf(-h1));
            tb[1344 + task] = g1 / (1.f + __expf(-w1v));
        }
    }
    __syncthreads();
    {
        const float4* ts = (const float4*)tb;
        float4* td = (float4*)(tbl + (size_t)gq * TBLN);
        for (int i = t; i < 448; i += 256) td[i] = ts[i];
    }
    const float* cH0 = tb;
    const float* cW0 = tb + 448;
    const float* cH1 = tb + 896;
    const float* cW1 = tb + 1344;
    #pragma unroll 1
    for (int i = 0; i < 8; ++i) {
        const float4* xp4 = (const float4*)(x + (size_t)(q0 + i) * PLANE);
        const float4* a4 = (const float4*)(cW0 + i * 56);
        const float4* b4 = (const float4*)(cW1 + i * 56);
        const float* h0p = cH0 + i * 56;
        const float* h1p = cH1 + i * 56;
        float acc = 0.f;
        for (int j = t; j < PLANE4; j += 256) {
            float4 v = xp4[j];
            int h = j / 14, wq = j - h * 14;
            float h0 = h0p[h], h1 = h1p[h];
            float4 a = a4[wq], b = b4[wq];
            acc += v.x * (h0 * a.x + h1 * b.x) + v.y * (h0 * a.y + h1 * b.y)
                 + v.z * (h0 * a.z + h1 * b.z) + v.w * (h0 * a.w + h1 * b.w);
        }
        float s = wave_sum(acc);
        if (ln == 0) part[i * 4 + wv] = s;
    }
    __syncthreads();
    if (t < 8)
        tvec[q0 + t] = (part[t * 4] + part[t * 4 + 1] + part[t * 4 + 2] + part[t * 4 + 3]) * (1.f / PLANE);
}

__global__ __launch_bounds__(256) void k_final(const float* __restrict__ x,
        const float* __restrict__ tbl, const float* __restrict__ tvec,
        const float* __restrict__ cw1, const float* __restrict__ cw2,
        const float* __restrict__ cb2, float* __restrict__ out) {
    __shared__ __align__(16) float tb[1792];
    __shared__ __align__(16) float part_h[256];
    __shared__ float hid[64];
    __shared__ float sS[8];
    const int t = threadIdx.x;
    const int gq = blockIdx.x;
    const int q0 = gq * 8, qn = q0 >> 8, qc0 = q0 & 255;
    {
        const float4* ts = (const float4*)(tbl + (size_t)gq * TBLN);
        float4* td = (float4*)tb;
        for (int i = t; i < 448; i += 256) td[i] = ts[i];
    }
    {
        int j = t & 63, ch = t >> 6;
        const float* tv = tvec + qn * CB + ch * 64;
        const float* wp = cw1 + (size_t)j * CB + ch * 64;
        float a = 0.f;
        #pragma unroll 8
        for (int c = 0; c < 64; ++c) a += tv[c] * wp[c];
        part_h[j * 4 + ch] = a;
    }
    __syncthreads();
    if (t < 64) {
        float4 p = *(const float4*)(part_h + t * 4);
        hid[t] = fmaxf(p.x + p.y + p.z + p.w, 0.f);
    }
    __syncthreads();
    if (t < 8) {
        int c = qc0 + t;
        float a = cb2[c];
        #pragma unroll 8
        for (int j = 0; j < 64; ++j) a += hid[j] * cw2[c * 64 + j];
        sS[t] = 1.f / (1.f + __expf(-a));
    }
    __syncthreads();
    const float* cH0 = tb;
    const float* cW0 = tb + 448;
    const float* cH1 = tb + 896;
    const float* cW1 = tb + 1344;
    #pragma unroll 1
    for (int i = 0; i < 8; ++i) {
        const float sv = sS[i];
        const float4* xp4 = (const float4*)(x + (size_t)(q0 + i) * PLANE);
        float4* op4 = (float4*)(out + (size_t)(q0 + i) * PLANE);
        const float4* a4 = (const float4*)(cW0 + i * 56);
        const float4* b4 = (const float4*)(cW1 + i * 56);
        const float* h0p = cH0 + i * 56;
        const float* h1p = cH1 + i * 56;
        for (int j = t; j < PLANE4; j += 256) {
            float4 v = xp4[j];
            int h = j / 14, wq = j - h * 14;
            float h0 = h0p[h] * sv, h1 = h1p[h] * sv;
            float4 a = a4[wq], b = b4[wq];
            float4 rr;
            rr.x = v.x * (h0 * a.x + h1 * b.x + 1.f);
            rr.y = v.y * (h0 * a.y + h1 * b.y + 1.f);
            rr.z = v.z * (h0 * a.z + h1 * b.z + 1.f);
            rr.w = v.w * (h0 * a.w + h1 * b.w + 1.f);
            op4[j] = rr;
        }
    }
}

extern "C" void kernel_launch(void* const* d_in, const int* in_sizes, int n_in,
                              void* d_out, int out_size, void* d_ws, size_t ws_size,
                              hipStream_t stream) {
    const float* x     = (const float*)d_in[0];
    const float* w1    = (const float*)d_in[1];
    const float* b1    = (const float*)d_in[2];
    const float* gamma = (const float*)d_in[3];
    const float* beta  = (const float*)d_in[4];
    const float* rmean = (const float*)d_in[5];
    const float* rvar  = (const float*)d_in[6];
    const float* wh    = (const float*)d_in[7];
    const float* bh    = (const float*)d_in[8];
    const float* ww    = (const float*)d_in[9];
    const float* bw    = (const float*)d_in[10];
    const float* gw1   = (const float*)d_in[11];
    const float* gw2   = (const float*)d_in[12];
    const float* gb2   = (const float*)d_in[13];
    const float* cw1   = (const float*)d_in[14];
    const float* cw2   = (const float*)d_in[15];
    const float* cb2   = (const float*)d_in[16];
    float* out = (float*)d_out;

    float* w = (float*)d_ws;
    float* ph   = w;                          // POOLSZ each
    float* pw   = ph + POOLSZ;
    float* mh   = pw + POOLSZ;
    float* mw   = mh + POOLSZ;
    float* gap  = mw + POOLSZ;                // NB*CB
    float* tvec = gap + NB * CB;              // NB*CB
    float* sbuf = tvec + NB * CB;             // NB*CB
    float* ybuf = sbuf + NB * CB;             // NB*1792
    float* gbuf = ybuf + NB * 1792;           // 64
    int*   sync = (int*)(gbuf + 64);          // 128 ints
    float* tbl  = (float*)(sync + 128);       // NCHUNK*TBLN (fallback only)

    static int g_mode = 0;                    // 0 undecided, 1 coop, -1 fallback
    if (g_mode == 0) {
        int nb = 0;
        hipError_t qe = hipOccupancyMaxActiveBlocksPerMultiprocessor(
                &nb, (const void*)k_one, 256, 0);
        g_mode = (qe == hipSuccess && nb >= 4) ? 1 : -1;
    }

    bool done = false;
    if (g_mode == 1) {
        hipError_t me = hipMemsetAsync(sync, 0, 128 * sizeof(int), stream);
        if (me == hipSuccess) {
            KP kp;
            kp.x = x; kp.w1 = w1; kp.b1 = b1; kp.gamma = gamma; kp.beta = beta;
            kp.rmean = rmean; kp.rvar = rvar; kp.wh = wh; kp.bh = bh; kp.ww = ww;
            kp.bw = bw; kp.gw1 = gw1; kp.gw2 = gw2; kp.gb2 = gb2; kp.cw1 = cw1;
            kp.cw2 = cw2; kp.cb2 = cb2;
            kp.ph = ph; kp.pw = pw; kp.mh = mh; kp.mw = mw; kp.gap = gap;
            kp.tvec = tvec; kp.sbuf = sbuf; kp.ybuf = ybuf; kp.gbuf = gbuf;
            kp.sync = sync; kp.out = out;
            void* args[] = { (void*)&kp };
            hipError_t e = hipLaunchCooperativeKernel((const void*)k_one,
                    dim3(NCHUNK), dim3(256), args, 0, stream);
            if (e == hipSuccess) done = true;
            else { (void)hipGetLastError(); g_mode = -1; }
        } else { (void)hipGetLastError(); g_mode = -1; }
    }

    if (!done) {
        k_pool<<<4096, 256, 0, stream>>>(x, ph, pw, mh, mw, gap);
        k_bt<<<1024, 256, 0, stream>>>(x, ph, pw, mh, mw, gap,
                                       w1, b1, gamma, beta, rmean, rvar,
                                       gw1, gw2, gb2, wh, bh, ww, bw,
                                       tvec, tbl);
        k_final<<<1024, 256, 0, stream>>>(x, tbl, tvec, cw1, cw2, cb2, out);
    }
}